// Round 22
// baseline (1367.509 us; speedup 1.0000x reference)
//
#include <hip/hip_runtime.h>

#define N_NODES 150000
#define N_EDGES 500000
#define D 128
#define D2 256
#define NLAYER 5
#define NB1 586    // ceil(N_NODES/256)
#define NROWT 9375 // N_NODES/16 (exact)
#define NBLK1 512  // gemm1s persistent blocks
#define NBLK2 512  // gemm12 persistent blocks
#define NBUCK 33   // degree buckets 0..32+

typedef __attribute__((ext_vector_type(8))) short bf16x8;
typedef __attribute__((ext_vector_type(4))) float f32x4;
typedef __attribute__((ext_vector_type(4))) unsigned short ushort4v;
typedef __attribute__((ext_vector_type(8))) unsigned short ushort8v;
typedef __attribute__((ext_vector_type(4))) unsigned int u32x4;

__device__ __forceinline__ unsigned short f2bf(float f) {
    unsigned int u = __builtin_bit_cast(unsigned int, f);
    u += 0x7fffu + ((u >> 16) & 1u);
    return (unsigned short)(u >> 16);
}
// HW path: compiler lowers to v_cvt_pk_bf16_f32 and fuses pairs (m240)
__device__ __forceinline__ unsigned short f2bf_hw(float f) {
    return __builtin_bit_cast(unsigned short, (__bf16)f);
}
__device__ __forceinline__ float bf2f(unsigned short s) {
    unsigned int u = ((unsigned int)s) << 16;
    return __builtin_bit_cast(float, u);
}

// ---------------- weight transpose + bf16 convert ----------------
__global__ __launch_bounds__(256) void prepw_kernel(const float* __restrict__ W1,
        const float* __restrict__ W2, unsigned short* __restrict__ w1t,
        unsigned short* __restrict__ w2t) {
    int i = blockIdx.x * 256 + threadIdx.x;
    if (i < NLAYER * D2 * D) {
        int l = i / (D2 * D);
        int rem = i % (D2 * D);
        int n = rem / D;
        int k = rem % D;
        w1t[i] = f2bf(W1[(l * D + k) * D2 + n]);
    }
    if (i < NLAYER * D * D2) {
        int l = i / (D * D2);
        int rem = i % (D * D2);
        int n = rem / D2;
        int k = rem % D2;
        w2t[i] = f2bf(W2[(l * D2 + k) * D + n]);
    }
}

// ---------------- bond combo table ----------------
__global__ __launch_bounds__(128) void combo_kernel(const float* __restrict__ bemb,
        float* __restrict__ combo) {
    int b = blockIdx.x;            // l*216 + p
    int l = b / 216, p = b % 216;
    int a0 = p % 6, a1 = (p / 6) % 6, a2 = p / 36;
    int d = threadIdx.x;
    combo[b * D + d] = bemb[((l * 3 + 0) * 6 + a0) * D + d]
                     + bemb[((l * 3 + 1) * 6 + a1) * D + d]
                     + bemb[((l * 3 + 2) * 6 + a2) * D + d];
}

// ---------------- atom encoder (bf16 h only) ----------------
__global__ __launch_bounds__(256) void atom_enc_kernel(const int* __restrict__ x,
        const float* __restrict__ aemb, unsigned short* __restrict__ hbf) {
    int node = blockIdx.x * 8 + (threadIdx.x >> 5);
    int t = threadIdx.x & 31;
    int d0 = t * 4;
    f32x4 s = {0, 0, 0, 0};
#pragma unroll
    for (int f = 0; f < 9; ++f) {
        int xi = x[node * 9 + f];
        f32x4 v = *(const f32x4*)(aemb + (size_t)(f * 119 + xi) * D + d0);
        s[0] += v[0]; s[1] += v[1]; s[2] += v[2]; s[3] += v[3];
    }
    ushort4v o;
#pragma unroll
    for (int j = 0; j < 4; ++j) o[j] = f2bf_hw(s[j]);
    *(ushort4v*)(hbf + (size_t)node * D + d0) = o;
}

// ---------------- CSR build ----------------
__global__ __launch_bounds__(256) void hist_kernel(const int* __restrict__ ei,
        int* __restrict__ deg) {
    int e = blockIdx.x * 256 + threadIdx.x;
    if (e < N_EDGES) atomicAdd(&deg[ei[N_EDGES + e]], 1);
}

__global__ __launch_bounds__(256) void scan1_kernel(const int* __restrict__ deg,
        int* __restrict__ part, int* __restrict__ bsum) {
    __shared__ int sd[256];
    int tid = threadIdx.x;
    int i = blockIdx.x * 256 + tid;
    int v = (i < N_NODES) ? deg[i] : 0;
    sd[tid] = v;
    __syncthreads();
    for (int off = 1; off < 256; off <<= 1) {
        int t = (tid >= off) ? sd[tid - off] : 0;
        __syncthreads();
        sd[tid] += t;
        __syncthreads();
    }
    if (i < N_NODES) part[i] = sd[tid] - v;
    if (tid == 255) bsum[blockIdx.x] = sd[255];
}

__global__ __launch_bounds__(1024) void scan2_kernel(const int* __restrict__ bsum,
        int* __restrict__ boff) {
    __shared__ int sd[1024];
    int tid = threadIdx.x;
    int v = (tid < NB1) ? bsum[tid] : 0;
    sd[tid] = v;
    __syncthreads();
    for (int off = 1; off < 1024; off <<= 1) {
        int t = (tid >= off) ? sd[tid - off] : 0;
        __syncthreads();
        sd[tid] += t;
        __syncthreads();
    }
    if (tid < NB1) boff[tid] = sd[tid] - v;
}

__global__ __launch_bounds__(256) void scan3_kernel(const int* __restrict__ part,
        const int* __restrict__ boff, int* __restrict__ row_start) {
    int i = blockIdx.x * 256 + threadIdx.x;
    if (i < N_NODES) row_start[i] = part[i] + boff[i >> 8];
}

__global__ __launch_bounds__(256) void bin_kernel(const int* __restrict__ ei,
        const int* __restrict__ ea, const int* __restrict__ row_start,
        int* __restrict__ cursor, int* __restrict__ bins) {
    int e = blockIdx.x * 256 + threadIdx.x;
    if (e >= N_EDGES) return;
    int dst = ei[N_EDGES + e];
    int pos = row_start[dst] + atomicAdd(&cursor[dst], 1);
    int pack = ea[e * 3 + 0] + ea[e * 3 + 1] * 6 + ea[e * 3 + 2] * 36;
    bins[pos] = ei[e] | (pack << 18);
}

// ---------------- degree-bucketed permutation (two-level counting sort) ----------------
__global__ __launch_bounds__(256) void bucket_hist_kernel(const int* __restrict__ deg,
        int* __restrict__ bcnt) {
    int i = blockIdx.x * 256 + threadIdx.x;
    if (i < N_NODES) {
        int b = min(deg[i], NBUCK - 1);
        atomicAdd(&bcnt[b], 1);
    }
}

__global__ void bucket_scan_kernel(const int* __restrict__ bcnt, int* __restrict__ bstart) {
    if (threadIdx.x == 0) {
        int acc = 0;
        for (int b = 0; b < NBUCK; ++b) { bstart[b] = acc; acc += bcnt[b]; }
    }
}

__global__ __launch_bounds__(256) void bucket_scatter_kernel(const int* __restrict__ deg,
        const int* __restrict__ bstart, int* __restrict__ gcur, int* __restrict__ perm) {
    __shared__ int lcnt[NBUCK], lbase[NBUCK];
    int tid = threadIdx.x;
    if (tid < NBUCK) lcnt[tid] = 0;
    __syncthreads();
    int i = blockIdx.x * 256 + tid;
    int b = 0, myoff = 0;
    bool valid = i < N_NODES;
    if (valid) {
        b = min(deg[i], NBUCK - 1);
        myoff = atomicAdd(&lcnt[b], 1);
    }
    __syncthreads();
    if (tid < NBUCK && lcnt[tid] > 0)
        lbase[tid] = atomicAdd(&gcur[tid], lcnt[tid]);
    __syncthreads();
    if (valid)
        perm[bstart[b] + lbase[b] + myoff] = i;
}

// ---------------- aggregation + A-build (deg-bucketed, 4 nodes/wave, 2-deep pipeline) ----------------
__global__ __launch_bounds__(256) void aggr_kernel(const int* __restrict__ perm,
        const int* __restrict__ row_start,
        const int* __restrict__ deg, const int* __restrict__ bins,
        const float* __restrict__ combo, const unsigned short* __restrict__ hbf,
        const float* __restrict__ epsp, unsigned short* __restrict__ A) {
    int wid = threadIdx.x >> 6;
    int lane = threadIdx.x & 63;
    int sub = lane >> 4;               // node slot 0..3 within wave
    int t = lane & 15;
    int d0 = t * 8;
    int node = perm[blockIdx.x * 16 + wid * 4 + sub];
    float ke = 1.0f + epsp[0];
    int start = row_start[node];
    int dg = deg[node];
    f32x4 s0 = {0, 0, 0, 0}, s1 = {0, 0, 0, 0};

    // pipeline state: e_nxt = bins entry for i+1; cur data for i
    int e_cur = (dg > 0) ? bins[start] : 0;
    int e_nxt = (dg > 1) ? bins[start + 1] : 0;
    ushort8v hv = {0,0,0,0,0,0,0,0};
    f32x4 c0 = {0,0,0,0}, c1 = {0,0,0,0};
    if (dg > 0) {
        int src = e_cur & 0x3FFFF;
        int pack = e_cur >> 18;
        hv = *(const ushort8v*)(hbf + (size_t)src * D + d0);
        c0 = *(const f32x4*)(combo + pack * D + d0);
        c1 = *(const f32x4*)(combo + pack * D + d0 + 4);
    }
    for (int i = 0; i < dg; ++i) {
        int e2 = (i + 2 < dg) ? bins[start + i + 2] : 0;
        ushort8v hvn = {0,0,0,0,0,0,0,0};
        f32x4 c0n = {0,0,0,0}, c1n = {0,0,0,0};
        if (i + 1 < dg) {
            int src = e_nxt & 0x3FFFF;
            int pack = e_nxt >> 18;
            hvn = *(const ushort8v*)(hbf + (size_t)src * D + d0);
            c0n = *(const f32x4*)(combo + pack * D + d0);
            c1n = *(const f32x4*)(combo + pack * D + d0 + 4);
        }
#pragma unroll
        for (int j = 0; j < 4; ++j) {
            s0[j] += fmaxf(bf2f(hv[j]) + c0[j], 0.f);
            s1[j] += fmaxf(bf2f(hv[j + 4]) + c1[j], 0.f);
        }
        hv = hvn; c0 = c0n; c1 = c1n;
        e_nxt = e2;
    }
    ushort8v hs = *(const ushort8v*)(hbf + (size_t)node * D + d0);
    ushort8v o;
#pragma unroll
    for (int j = 0; j < 4; ++j) {
        o[j]     = f2bf_hw(ke * bf2f(hs[j]) + s0[j]);
        o[j + 4] = f2bf_hw(ke * bf2f(hs[j + 4]) + s1[j]);
    }
    *(ushort8v*)(A + (size_t)node * D + d0) = o;
}

// ---------------- GEMM1-STATS (persistent, B-resident, NO z1 store) ----------------
__global__ __launch_bounds__(256) void gemm1s_kernel(const unsigned short* __restrict__ A,
        const unsigned short* __restrict__ w1t, const float* __restrict__ b1,
        float* __restrict__ part1) {
    int wave = threadIdx.x >> 6;
    int lane = threadIdx.x & 63;
    int l15 = lane & 15;
    int kg = lane >> 4;

    bf16x8 B[4][4];
    float bias[4];
#pragma unroll
    for (int t = 0; t < 4; ++t) {
        int col = (wave * 4 + t) * 16 + l15;
        bias[t] = b1[col];
#pragma unroll
        for (int kk = 0; kk < 4; ++kk)
            B[t][kk] = *(const bf16x8*)(w1t + (size_t)col * D + kk * 32 + kg * 8);
    }
    float s[4] = {0.f, 0.f, 0.f, 0.f}, q[4] = {0.f, 0.f, 0.f, 0.f};

    int rt = blockIdx.x;
    bf16x8 afn[4];
    {
        int row = rt * 16 + l15;
#pragma unroll
        for (int kk = 0; kk < 4; ++kk)
            afn[kk] = *(const bf16x8*)(A + (size_t)row * D + kk * 32 + kg * 8);
    }
    while (rt < NROWT) {
        int rtn = rt + NBLK1;
        bf16x8 af[4];
#pragma unroll
        for (int kk = 0; kk < 4; ++kk) af[kk] = afn[kk];
        if (rtn < NROWT) {
            int row = rtn * 16 + l15;
#pragma unroll
            for (int kk = 0; kk < 4; ++kk)
                afn[kk] = *(const bf16x8*)(A + (size_t)row * D + kk * 32 + kg * 8);
        }
        f32x4 acc[4];
#pragma unroll
        for (int t = 0; t < 4; ++t) acc[t] = (f32x4){0.f, 0.f, 0.f, 0.f};
#pragma unroll
        for (int kk = 0; kk < 4; ++kk)
#pragma unroll
            for (int t = 0; t < 4; ++t)
                acc[t] = __builtin_amdgcn_mfma_f32_16x16x32_bf16(af[kk], B[t][kk], acc[t], 0, 0, 0);
#pragma unroll
        for (int t = 0; t < 4; ++t) {
#pragma unroll
            for (int r = 0; r < 4; ++r) {
                float va = acc[t][r] + bias[t];
                s[t] += va;
                q[t] = fmaf(va, va, q[t]);
            }
        }
        rt = rtn;
    }
#pragma unroll
    for (int t = 0; t < 4; ++t) {
        s[t] += __shfl_xor(s[t], 16); s[t] += __shfl_xor(s[t], 32);
        q[t] += __shfl_xor(q[t], 16); q[t] += __shfl_xor(q[t], 32);
        if (kg == 0) {
            int col = (wave * 4 + t) * 16 + l15;
            part1[(size_t)blockIdx.x * 512 + col] = s[t];
            part1[(size_t)blockIdx.x * 512 + 256 + col] = q[t];
        }
    }
}

// ---------------- reduce partials + finalize BN ----------------
// outputs: scale(f32), shift(f32), shpb(bf16 of shift/scale, for BN1-fold)
__global__ __launch_bounds__(256) void reduce_finalize_kernel(const float* __restrict__ part,
        int nblk, int C, const float* __restrict__ g, const float* __restrict__ bb,
        float* __restrict__ scale, float* __restrict__ shift,
        unsigned short* __restrict__ shpb) {
    int c = blockIdx.x;
    int tid = threadIdx.x;
    float s = 0.f, q = 0.f;
    for (int i = tid; i < nblk; i += 256) {
        s += part[(size_t)i * 2 * C + c];
        q += part[(size_t)i * 2 * C + C + c];
    }
#pragma unroll
    for (int off = 1; off < 64; off <<= 1) {
        s += __shfl_xor(s, off);
        q += __shfl_xor(q, off);
    }
    __shared__ float rs[4], rq[4];
    int w = tid >> 6;
    if ((tid & 63) == 0) { rs[w] = s; rq[w] = q; }
    __syncthreads();
    if (tid == 0) {
        s = rs[0] + rs[1] + rs[2] + rs[3];
        q = rq[0] + rq[1] + rq[2] + rq[3];
        float inv_n = 1.0f / (float)N_NODES;
        float mean = s * inv_n;
        float var = q * inv_n - mean * mean;
        float sc = g[c] * rsqrtf(var + 1e-5f);
        float sh = bb[c] - mean * sc;
        scale[c] = sc;
        shift[c] = sh;
        shpb[c] = f2bf(sh / sc);
    }
}

// ---------------- FUSED GEMM12 (double-buffered z1t, 1 barrier/tile) ----------------
// z2 = bf16( relu(z1 + sh/sc) @ (diag(sc)*W2) + b2 ), z1 = A@W1 + b1 recomputed per tile
__global__ __launch_bounds__(256) void gemm12_kernel(const unsigned short* __restrict__ A,
        const unsigned short* __restrict__ w1t, const float* __restrict__ b1,
        const unsigned short* __restrict__ shpb, const float* __restrict__ scale1,
        const unsigned short* __restrict__ w2t, const float* __restrict__ b2,
        unsigned short* __restrict__ z2, float* __restrict__ part2) {
    __shared__ unsigned short z1t[2][16][264];  // double buffer: 1 barrier per tile
    __shared__ unsigned short sm2[4][16][44];
    int wave = threadIdx.x >> 6;
    int lane = threadIdx.x & 63;
    int l15 = lane & 15;
    int kg = lane >> 4;
    int rrow = lane >> 2;          // 0..15
    int rcol = (lane & 3) * 8;     // 0..31 step 8

    // gemm1 part: wave owns z1 cols [wave*64, wave*64+64)
    bf16x8 B1[4][4];
    float bs1[4];                  // b1 + sh/sc  (combined pre-relu shift)
#pragma unroll
    for (int t = 0; t < 4; ++t) {
        int col = (wave * 4 + t) * 16 + l15;
        bs1[t] = b1[col] + bf2f(shpb[col]);
#pragma unroll
        for (int kk = 0; kk < 4; ++kk)
            B1[t][kk] = *(const bf16x8*)(w1t + (size_t)col * D + kk * 32 + kg * 8);
    }
    // gemm2 part: wave owns z2 cols [wave*32, wave*32+32); B2 scaled by scale1 (per-k)
    bf16x8 B2[2][8];
    float bias2[2];
#pragma unroll
    for (int t = 0; t < 2; ++t) {
        int col = (wave * 2 + t) * 16 + l15;
        bias2[t] = b2[col];
#pragma unroll
        for (int kk = 0; kk < 8; ++kk) {
            bf16x8 raw = *(const bf16x8*)(w2t + (size_t)col * D2 + kk * 32 + kg * 8);
            int k0 = kk * 32 + kg * 8;
            const f32x4* sp = (const f32x4*)(scale1 + k0);
            f32x4 s0 = sp[0], s1 = sp[1];
            ushort8v bw;
#pragma unroll
            for (int j = 0; j < 4; ++j) {
                bw[j]     = f2bf_hw(bf2f((unsigned short)raw[j]) * s0[j]);
                bw[j + 4] = f2bf_hw(bf2f((unsigned short)raw[j + 4]) * s1[j]);
            }
            B2[t][kk] = __builtin_bit_cast(bf16x8, bw);
        }
    }

    float s[2] = {0.f, 0.f}, q[2] = {0.f, 0.f};

    int rt = blockIdx.x;
    int p = 0;
    bf16x8 afn[4];
    {
        int row = rt * 16 + l15;
#pragma unroll
        for (int kk = 0; kk < 4; ++kk)
            afn[kk] = *(const bf16x8*)(A + (size_t)row * D + kk * 32 + kg * 8);
    }
    while (rt < NROWT) {
        int rtn = rt + NBLK2;
        bf16x8 af[4];
#pragma unroll
        for (int kk = 0; kk < 4; ++kk) af[kk] = afn[kk];
        if (rtn < NROWT) {
            int row = rtn * 16 + l15;
#pragma unroll
            for (int kk = 0; kk < 4; ++kk)
                afn[kk] = *(const bf16x8*)(A + (size_t)row * D + kk * 32 + kg * 8);
        }
        // z1 tile (16 rows x 64 cols per wave)
        f32x4 acc1[4];
#pragma unroll
        for (int t = 0; t < 4; ++t) acc1[t] = (f32x4){0.f, 0.f, 0.f, 0.f};
#pragma unroll
        for (int kk = 0; kk < 4; ++kk)
#pragma unroll
            for (int t = 0; t < 4; ++t)
                acc1[t] = __builtin_amdgcn_mfma_f32_16x16x32_bf16(af[kk], B1[t][kk], acc1[t], 0, 0, 0);
        // write to buffer p (other buffer may still be being read — safe)
#pragma unroll
        for (int t = 0; t < 4; ++t) {
            int col = (wave * 4 + t) * 16 + l15;
#pragma unroll
            for (int r = 0; r < 4; ++r)
                z1t[p][kg * 4 + r][col] = f2bf_hw(fmaxf(acc1[t][r] + bs1[t], 0.f));
        }
        __syncthreads();   // buffer p complete for all waves
        // gemm2: read K=256 fragments from LDS buffer p
        f32x4 acc2[2];
        acc2[0] = (f32x4){0.f, 0.f, 0.f, 0.f};
        acc2[1] = (f32x4){0.f, 0.f, 0.f, 0.f};
#pragma unroll
        for (int kk = 0; kk < 8; ++kk) {
            bf16x8 a2 = __builtin_bit_cast(bf16x8, *(const ushort8v*)&z1t[p][l15][kk * 32 + kg * 8]);
            acc2[0] = __builtin_amdgcn_mfma_f32_16x16x32_bf16(a2, B2[0][kk], acc2[0], 0, 0, 0);
            acc2[1] = __builtin_amdgcn_mfma_f32_16x16x32_bf16(a2, B2[1][kk], acc2[1], 0, 0, 0);
        }
#pragma unroll
        for (int t = 0; t < 2; ++t) {
#pragma unroll
            for (int r = 0; r < 4; ++r) {
                float va = acc2[t][r] + bias2[t];
                s[t] += va;
                q[t] = fmaf(va, va, q[t]);
                sm2[wave][kg * 4 + r][t * 16 + l15] = f2bf_hw(va);
            }
        }
        ushort8v v0 = *(const ushort8v*)&sm2[wave][rrow][rcol];
        *(ushort8v*)(z2 + (size_t)(rt * 16 + rrow) * D + wave * 32 + rcol) = v0;
        p ^= 1;
        rt = rtn;
    }
#pragma unroll
    for (int t = 0; t < 2; ++t) {
        s[t] += __shfl_xor(s[t], 16); s[t] += __shfl_xor(s[t], 32);
        q[t] += __shfl_xor(q[t], 16); q[t] += __shfl_xor(q[t], 32);
        if (kg == 0) {
            int col = (wave * 2 + t) * 16 + l15;
            part2[(size_t)blockIdx.x * 256 + col] = s[t];
            part2[(size_t)blockIdx.x * 256 + 128 + col] = q[t];
        }
    }
}

// ---------------- final: hbf = bf16(relu(bn2(z2)) + hbf)  [last: h_f32 = bn2(z2)+hbf] ----------------
__global__ __launch_bounds__(256) void final_kernel(const unsigned short* __restrict__ z2,
        const float* __restrict__ scale, const float* __restrict__ shift,
        unsigned short* __restrict__ hbf, float* __restrict__ hout, int last) {
    int i = blockIdx.x * 256 + threadIdx.x;
    int base = i * 8;
    int c = base & (D - 1);
    f32x4 sc0 = *(const f32x4*)(scale + c);
    f32x4 sc1 = *(const f32x4*)(scale + c + 4);
    f32x4 sh0 = *(const f32x4*)(shift + c);
    f32x4 sh1 = *(const f32x4*)(shift + c + 4);
    ushort8v zv = *(const ushort8v*)(z2 + base);
    ushort8v hv = *(const ushort8v*)(hbf + base);
    if (last) {
        f32x4 o0, o1;
#pragma unroll
        for (int j = 0; j < 4; ++j) {
            o0[j] = fmaf(bf2f(zv[j]), sc0[j], sh0[j]) + bf2f(hv[j]);
            o1[j] = fmaf(bf2f(zv[j + 4]), sc1[j], sh1[j]) + bf2f(hv[j + 4]);
        }
        *(f32x4*)(hout + base) = o0;
        *(f32x4*)(hout + base + 4) = o1;
    } else {
        ushort8v ob;
#pragma unroll
        for (int j = 0; j < 4; ++j) {
            float v0 = fmaxf(fmaf(bf2f(zv[j]), sc0[j], sh0[j]), 0.f) + bf2f(hv[j]);
            float v1 = fmaxf(fmaf(bf2f(zv[j + 4]), sc1[j], sh1[j]), 0.f) + bf2f(hv[j + 4]);
            ob[j] = f2bf_hw(v0);
            ob[j + 4] = f2bf_hw(v1);
        }
        *(ushort8v*)(hbf + base) = ob;
    }
}

extern "C" void kernel_launch(void* const* d_in, const int* in_sizes, int n_in,
                              void* d_out, int out_size, void* d_ws, size_t ws_size,
                              hipStream_t stream) {
    const int* x = (const int*)d_in[0];
    const int* ei = (const int*)d_in[1];
    const int* ea = (const int*)d_in[2];
    const float* aemb = (const float*)d_in[4];
    const float* bemb = (const float*)d_in[5];
    const float* eps = (const float*)d_in[6];
    const float* W1 = (const float*)d_in[7];
    const float* b1 = (const float*)d_in[8];
    const float* bn1g = (const float*)d_in[9];
    const float* bn1b = (const float*)d_in[10];
    const float* W2 = (const float*)d_in[11];
    const float* b2 = (const float*)d_in[12];
    const float* bng = (const float*)d_in[13];
    const float* bnb = (const float*)d_in[14];
    float* h = (float*)d_out;

    char* ws = (char*)d_ws;
    size_t off = 0;
    auto alloc = [&](size_t bytes) {
        void* p = ws + off;
        off += (bytes + 255) & ~(size_t)255;
        return p;
    };
    unsigned short* Az2 = (unsigned short*)alloc((size_t)N_NODES * D * 2);   // 38.4MB (A aliases z2)
    unsigned short* hbf = (unsigned short*)alloc((size_t)N_NODES * D * 2);   // 38.4MB bf16 h
    unsigned short* w1t = (unsigned short*)alloc((size_t)NLAYER * D2 * D * 2);
    unsigned short* w2t = (unsigned short*)alloc((size_t)NLAYER * D * D2 * 2);
    float* combo        = (float*)alloc((size_t)NLAYER * 216 * D * 4);
    int* bins           = (int*)alloc((size_t)N_EDGES * 4);
    int* row_start      = (int*)alloc((size_t)(NB1 * 256) * 4);
    int* deg            = (int*)alloc((size_t)(NB1 * 256) * 4);
    int* cursor         = (int*)alloc((size_t)(NB1 * 256) * 4);
    int* part           = (int*)alloc((size_t)(NB1 * 256) * 4);
    int* bsum           = (int*)alloc(1024 * 4);
    int* boff           = (int*)alloc(1024 * 4);
    int* perm           = (int*)alloc((size_t)(NB1 * 256) * 4);
    int* bcnt           = (int*)alloc(256 * 4);
    int* bstart         = (int*)alloc(256 * 4);
    int* gcur           = (int*)alloc(256 * 4);
    float* part1        = (float*)alloc((size_t)NBLK1 * 512 * 4);   // 1.0MB
    float* part2        = (float*)alloc((size_t)NBLK2 * 256 * 4);   // 0.5MB
    float* scale1 = (float*)alloc(256 * 4);
    float* shift1 = (float*)alloc(256 * 4);
    float* scale2 = (float*)alloc(128 * 4);
    float* shift2 = (float*)alloc(128 * 4);
    unsigned short* shp1 = (unsigned short*)alloc(256 * 2);
    unsigned short* shp2 = (unsigned short*)alloc(128 * 2);

    // one-time prep
    prepw_kernel<<<(NLAYER * D2 * D + 255) / 256, 256, 0, stream>>>(W1, W2, w1t, w2t);
    combo_kernel<<<NLAYER * 216, 128, 0, stream>>>(bemb, combo);
    atom_enc_kernel<<<N_NODES / 8, 256, 0, stream>>>(x, aemb, hbf);

    // CSR build (by dst) + degree-bucketed perm
    hipMemsetAsync(deg, 0, (size_t)(NB1 * 256) * 4, stream);
    hipMemsetAsync(cursor, 0, (size_t)(NB1 * 256) * 4, stream);
    hipMemsetAsync(bcnt, 0, 256 * 4, stream);
    hipMemsetAsync(gcur, 0, 256 * 4, stream);
    hist_kernel<<<(N_EDGES + 255) / 256, 256, 0, stream>>>(ei, deg);
    scan1_kernel<<<NB1, 256, 0, stream>>>(deg, part, bsum);
    scan2_kernel<<<1, 1024, 0, stream>>>(bsum, boff);
    scan3_kernel<<<NB1, 256, 0, stream>>>(part, boff, row_start);
    bin_kernel<<<(N_EDGES + 255) / 256, 256, 0, stream>>>(ei, ea, row_start, cursor, bins);
    bucket_hist_kernel<<<NB1, 256, 0, stream>>>(deg, bcnt);
    bucket_scan_kernel<<<1, 64, 0, stream>>>(bcnt, bstart);
    bucket_scatter_kernel<<<NB1, 256, 0, stream>>>(deg, bstart, gcur, perm);

    for (int l = 0; l < NLAYER; ++l) {
        aggr_kernel<<<N_NODES / 16, 256, 0, stream>>>(perm, row_start, deg, bins,
                combo + l * 216 * D, hbf, eps + l, Az2);
        gemm1s_kernel<<<NBLK1, 256, 0, stream>>>(Az2, w1t + l * D2 * D,
                b1 + l * D2, part1);
        reduce_finalize_kernel<<<256, 256, 0, stream>>>(part1, NBLK1, D2,
                bn1g + l * D2, bn1b + l * D2, scale1, shift1, shp1);
        gemm12_kernel<<<NBLK2, 256, 0, stream>>>(Az2, w1t + l * D2 * D,
                b1 + l * D2, shp1, scale1, w2t + l * D * D2, b2 + l * D, Az2, part2);
        reduce_finalize_kernel<<<128, 256, 0, stream>>>(part2, NBLK2, D,
                bng + l * D, bnb + l * D, scale2, shift2, shp2);
        final_kernel<<<(N_NODES * D / 8) / 256, 256, 0, stream>>>(Az2, scale2, shift2,
                hbf, h, (l == NLAYER - 1) ? 1 : 0);
    }
}

// Round 23
// 731.708 us; speedup vs baseline: 1.8689x; 1.8689x over previous
//
#include <hip/hip_runtime.h>

#define N_NODES 150000
#define N_EDGES 500000
#define D 128
#define D2 256
#define NLAYER 5
#define NB1 586    // ceil(N_NODES/256)
#define NROWT 9375 // N_NODES/16 (exact)
#define NBLK1 512  // gemm1s persistent blocks
#define NBLK2 512  // gemm12 persistent blocks
#define NBUCK 33   // degree buckets 0..32+

typedef __attribute__((ext_vector_type(8))) short bf16x8;
typedef __attribute__((ext_vector_type(4))) float f32x4;
typedef __attribute__((ext_vector_type(4))) unsigned short ushort4v;
typedef __attribute__((ext_vector_type(8))) unsigned short ushort8v;
typedef __attribute__((ext_vector_type(4))) unsigned int u32x4;

__device__ __forceinline__ unsigned short f2bf(float f) {
    unsigned int u = __builtin_bit_cast(unsigned int, f);
    u += 0x7fffu + ((u >> 16) & 1u);
    return (unsigned short)(u >> 16);
}
// HW path: compiler lowers to v_cvt_pk_bf16_f32 and fuses pairs (m240)
__device__ __forceinline__ unsigned short f2bf_hw(float f) {
    return __builtin_bit_cast(unsigned short, (__bf16)f);
}
__device__ __forceinline__ float bf2f(unsigned short s) {
    unsigned int u = ((unsigned int)s) << 16;
    return __builtin_bit_cast(float, u);
}

// ---------------- weight transpose + bf16 convert ----------------
__global__ __launch_bounds__(256) void prepw_kernel(const float* __restrict__ W1,
        const float* __restrict__ W2, unsigned short* __restrict__ w1t,
        unsigned short* __restrict__ w2t) {
    int i = blockIdx.x * 256 + threadIdx.x;
    if (i < NLAYER * D2 * D) {
        int l = i / (D2 * D);
        int rem = i % (D2 * D);
        int n = rem / D;
        int k = rem % D;
        w1t[i] = f2bf(W1[(l * D + k) * D2 + n]);
    }
    if (i < NLAYER * D * D2) {
        int l = i / (D * D2);
        int rem = i % (D * D2);
        int n = rem / D2;
        int k = rem % D2;
        w2t[i] = f2bf(W2[(l * D2 + k) * D + n]);
    }
}

// ---------------- bond combo table ----------------
__global__ __launch_bounds__(128) void combo_kernel(const float* __restrict__ bemb,
        float* __restrict__ combo) {
    int b = blockIdx.x;            // l*216 + p
    int l = b / 216, p = b % 216;
    int a0 = p % 6, a1 = (p / 6) % 6, a2 = p / 36;
    int d = threadIdx.x;
    combo[b * D + d] = bemb[((l * 3 + 0) * 6 + a0) * D + d]
                     + bemb[((l * 3 + 1) * 6 + a1) * D + d]
                     + bemb[((l * 3 + 2) * 6 + a2) * D + d];
}

// ---------------- atom encoder (bf16 h only) ----------------
__global__ __launch_bounds__(256) void atom_enc_kernel(const int* __restrict__ x,
        const float* __restrict__ aemb, unsigned short* __restrict__ hbf) {
    int node = blockIdx.x * 8 + (threadIdx.x >> 5);
    int t = threadIdx.x & 31;
    int d0 = t * 4;
    f32x4 s = {0, 0, 0, 0};
#pragma unroll
    for (int f = 0; f < 9; ++f) {
        int xi = x[node * 9 + f];
        f32x4 v = *(const f32x4*)(aemb + (size_t)(f * 119 + xi) * D + d0);
        s[0] += v[0]; s[1] += v[1]; s[2] += v[2]; s[3] += v[3];
    }
    ushort4v o;
#pragma unroll
    for (int j = 0; j < 4; ++j) o[j] = f2bf_hw(s[j]);
    *(ushort4v*)(hbf + (size_t)node * D + d0) = o;
}

// ---------------- CSR build ----------------
__global__ __launch_bounds__(256) void hist_kernel(const int* __restrict__ ei,
        int* __restrict__ deg) {
    int e = blockIdx.x * 256 + threadIdx.x;
    if (e < N_EDGES) atomicAdd(&deg[ei[N_EDGES + e]], 1);
}

__global__ __launch_bounds__(256) void scan1_kernel(const int* __restrict__ deg,
        int* __restrict__ part, int* __restrict__ bsum) {
    __shared__ int sd[256];
    int tid = threadIdx.x;
    int i = blockIdx.x * 256 + tid;
    int v = (i < N_NODES) ? deg[i] : 0;
    sd[tid] = v;
    __syncthreads();
    for (int off = 1; off < 256; off <<= 1) {
        int t = (tid >= off) ? sd[tid - off] : 0;
        __syncthreads();
        sd[tid] += t;
        __syncthreads();
    }
    if (i < N_NODES) part[i] = sd[tid] - v;
    if (tid == 255) bsum[blockIdx.x] = sd[255];
}

__global__ __launch_bounds__(1024) void scan2_kernel(const int* __restrict__ bsum,
        int* __restrict__ boff) {
    __shared__ int sd[1024];
    int tid = threadIdx.x;
    int v = (tid < NB1) ? bsum[tid] : 0;
    sd[tid] = v;
    __syncthreads();
    for (int off = 1; off < 1024; off <<= 1) {
        int t = (tid >= off) ? sd[tid - off] : 0;
        __syncthreads();
        sd[tid] += t;
        __syncthreads();
    }
    if (tid < NB1) boff[tid] = sd[tid] - v;
}

__global__ __launch_bounds__(256) void scan3_kernel(const int* __restrict__ part,
        const int* __restrict__ boff, int* __restrict__ row_start) {
    int i = blockIdx.x * 256 + threadIdx.x;
    if (i < N_NODES) row_start[i] = part[i] + boff[i >> 8];
}

__global__ __launch_bounds__(256) void bin_kernel(const int* __restrict__ ei,
        const int* __restrict__ ea, const int* __restrict__ row_start,
        int* __restrict__ cursor, int* __restrict__ bins) {
    int e = blockIdx.x * 256 + threadIdx.x;
    if (e >= N_EDGES) return;
    int dst = ei[N_EDGES + e];
    int pos = row_start[dst] + atomicAdd(&cursor[dst], 1);
    int pack = ea[e * 3 + 0] + ea[e * 3 + 1] * 6 + ea[e * 3 + 2] * 36;
    bins[pos] = ei[e] | (pack << 18);
}

// ---------------- degree-bucketed permutation (two-level counting sort) ----------------
// LDS-local histogram, one global add per bucket per block (round-3 contention lesson)
__global__ __launch_bounds__(256) void bucket_hist_kernel(const int* __restrict__ deg,
        int* __restrict__ bcnt) {
    __shared__ int lcnt[NBUCK];
    int tid = threadIdx.x;
    if (tid < NBUCK) lcnt[tid] = 0;
    __syncthreads();
    int i = blockIdx.x * 256 + tid;
    if (i < N_NODES)
        atomicAdd(&lcnt[min(deg[i], NBUCK - 1)], 1);
    __syncthreads();
    if (tid < NBUCK && lcnt[tid] > 0)
        atomicAdd(&bcnt[tid], lcnt[tid]);
}

__global__ void bucket_scan_kernel(const int* __restrict__ bcnt, int* __restrict__ bstart) {
    if (threadIdx.x == 0) {
        int acc = 0;
        for (int b = 0; b < NBUCK; ++b) { bstart[b] = acc; acc += bcnt[b]; }
    }
}

__global__ __launch_bounds__(256) void bucket_scatter_kernel(const int* __restrict__ deg,
        const int* __restrict__ bstart, int* __restrict__ gcur, int* __restrict__ perm) {
    __shared__ int lcnt[NBUCK], lbase[NBUCK];
    int tid = threadIdx.x;
    if (tid < NBUCK) lcnt[tid] = 0;
    __syncthreads();
    int i = blockIdx.x * 256 + tid;
    int b = 0, myoff = 0;
    bool valid = i < N_NODES;
    if (valid) {
        b = min(deg[i], NBUCK - 1);
        myoff = atomicAdd(&lcnt[b], 1);
    }
    __syncthreads();
    if (tid < NBUCK && lcnt[tid] > 0)
        lbase[tid] = atomicAdd(&gcur[tid], lcnt[tid]);
    __syncthreads();
    if (valid)
        perm[bstart[b] + lbase[b] + myoff] = i;
}

// ---------------- aggregation + A-build (deg-bucketed, 4 nodes/wave, 2-deep pipeline) ----------------
__global__ __launch_bounds__(256) void aggr_kernel(const int* __restrict__ perm,
        const int* __restrict__ row_start,
        const int* __restrict__ deg, const int* __restrict__ bins,
        const float* __restrict__ combo, const unsigned short* __restrict__ hbf,
        const float* __restrict__ epsp, unsigned short* __restrict__ A) {
    int wid = threadIdx.x >> 6;
    int lane = threadIdx.x & 63;
    int sub = lane >> 4;               // node slot 0..3 within wave
    int t = lane & 15;
    int d0 = t * 8;
    int node = perm[blockIdx.x * 16 + wid * 4 + sub];
    float ke = 1.0f + epsp[0];
    int start = row_start[node];
    int dg = deg[node];
    f32x4 s0 = {0, 0, 0, 0}, s1 = {0, 0, 0, 0};

    // pipeline state: e_nxt = bins entry for i+1; cur data for i
    int e_cur = (dg > 0) ? bins[start] : 0;
    int e_nxt = (dg > 1) ? bins[start + 1] : 0;
    ushort8v hv = {0,0,0,0,0,0,0,0};
    f32x4 c0 = {0,0,0,0}, c1 = {0,0,0,0};
    if (dg > 0) {
        int src = e_cur & 0x3FFFF;
        int pack = e_cur >> 18;
        hv = *(const ushort8v*)(hbf + (size_t)src * D + d0);
        c0 = *(const f32x4*)(combo + pack * D + d0);
        c1 = *(const f32x4*)(combo + pack * D + d0 + 4);
    }
    for (int i = 0; i < dg; ++i) {
        int e2 = (i + 2 < dg) ? bins[start + i + 2] : 0;
        ushort8v hvn = {0,0,0,0,0,0,0,0};
        f32x4 c0n = {0,0,0,0}, c1n = {0,0,0,0};
        if (i + 1 < dg) {
            int src = e_nxt & 0x3FFFF;
            int pack = e_nxt >> 18;
            hvn = *(const ushort8v*)(hbf + (size_t)src * D + d0);
            c0n = *(const f32x4*)(combo + pack * D + d0);
            c1n = *(const f32x4*)(combo + pack * D + d0 + 4);
        }
#pragma unroll
        for (int j = 0; j < 4; ++j) {
            s0[j] += fmaxf(bf2f(hv[j]) + c0[j], 0.f);
            s1[j] += fmaxf(bf2f(hv[j + 4]) + c1[j], 0.f);
        }
        hv = hvn; c0 = c0n; c1 = c1n;
        e_nxt = e2;
    }
    ushort8v hs = *(const ushort8v*)(hbf + (size_t)node * D + d0);
    ushort8v o;
#pragma unroll
    for (int j = 0; j < 4; ++j) {
        o[j]     = f2bf_hw(ke * bf2f(hs[j]) + s0[j]);
        o[j + 4] = f2bf_hw(ke * bf2f(hs[j + 4]) + s1[j]);
    }
    *(ushort8v*)(A + (size_t)node * D + d0) = o;
}

// ---------------- GEMM1-STATS (persistent, B-resident, NO z1 store) ----------------
__global__ __launch_bounds__(256) void gemm1s_kernel(const unsigned short* __restrict__ A,
        const unsigned short* __restrict__ w1t, const float* __restrict__ b1,
        float* __restrict__ part1) {
    int wave = threadIdx.x >> 6;
    int lane = threadIdx.x & 63;
    int l15 = lane & 15;
    int kg = lane >> 4;

    bf16x8 B[4][4];
    float bias[4];
#pragma unroll
    for (int t = 0; t < 4; ++t) {
        int col = (wave * 4 + t) * 16 + l15;
        bias[t] = b1[col];
#pragma unroll
        for (int kk = 0; kk < 4; ++kk)
            B[t][kk] = *(const bf16x8*)(w1t + (size_t)col * D + kk * 32 + kg * 8);
    }
    float s[4] = {0.f, 0.f, 0.f, 0.f}, q[4] = {0.f, 0.f, 0.f, 0.f};

    int rt = blockIdx.x;
    bf16x8 afn[4];
    {
        int row = rt * 16 + l15;
#pragma unroll
        for (int kk = 0; kk < 4; ++kk)
            afn[kk] = *(const bf16x8*)(A + (size_t)row * D + kk * 32 + kg * 8);
    }
    while (rt < NROWT) {
        int rtn = rt + NBLK1;
        bf16x8 af[4];
#pragma unroll
        for (int kk = 0; kk < 4; ++kk) af[kk] = afn[kk];
        if (rtn < NROWT) {
            int row = rtn * 16 + l15;
#pragma unroll
            for (int kk = 0; kk < 4; ++kk)
                afn[kk] = *(const bf16x8*)(A + (size_t)row * D + kk * 32 + kg * 8);
        }
        f32x4 acc[4];
#pragma unroll
        for (int t = 0; t < 4; ++t) acc[t] = (f32x4){0.f, 0.f, 0.f, 0.f};
#pragma unroll
        for (int kk = 0; kk < 4; ++kk)
#pragma unroll
            for (int t = 0; t < 4; ++t)
                acc[t] = __builtin_amdgcn_mfma_f32_16x16x32_bf16(af[kk], B[t][kk], acc[t], 0, 0, 0);
#pragma unroll
        for (int t = 0; t < 4; ++t) {
#pragma unroll
            for (int r = 0; r < 4; ++r) {
                float va = acc[t][r] + bias[t];
                s[t] += va;
                q[t] = fmaf(va, va, q[t]);
            }
        }
        rt = rtn;
    }
#pragma unroll
    for (int t = 0; t < 4; ++t) {
        s[t] += __shfl_xor(s[t], 16); s[t] += __shfl_xor(s[t], 32);
        q[t] += __shfl_xor(q[t], 16); q[t] += __shfl_xor(q[t], 32);
        if (kg == 0) {
            int col = (wave * 4 + t) * 16 + l15;
            part1[(size_t)blockIdx.x * 512 + col] = s[t];
            part1[(size_t)blockIdx.x * 512 + 256 + col] = q[t];
        }
    }
}

// ---------------- reduce partials + finalize BN ----------------
// outputs: scale(f32), shift(f32), shpb(bf16 of shift/scale, for BN1-fold)
__global__ __launch_bounds__(256) void reduce_finalize_kernel(const float* __restrict__ part,
        int nblk, int C, const float* __restrict__ g, const float* __restrict__ bb,
        float* __restrict__ scale, float* __restrict__ shift,
        unsigned short* __restrict__ shpb) {
    int c = blockIdx.x;
    int tid = threadIdx.x;
    float s = 0.f, q = 0.f;
    for (int i = tid; i < nblk; i += 256) {
        s += part[(size_t)i * 2 * C + c];
        q += part[(size_t)i * 2 * C + C + c];
    }
#pragma unroll
    for (int off = 1; off < 64; off <<= 1) {
        s += __shfl_xor(s, off);
        q += __shfl_xor(q, off);
    }
    __shared__ float rs[4], rq[4];
    int w = tid >> 6;
    if ((tid & 63) == 0) { rs[w] = s; rq[w] = q; }
    __syncthreads();
    if (tid == 0) {
        s = rs[0] + rs[1] + rs[2] + rs[3];
        q = rq[0] + rq[1] + rq[2] + rq[3];
        float inv_n = 1.0f / (float)N_NODES;
        float mean = s * inv_n;
        float var = q * inv_n - mean * mean;
        float sc = g[c] * rsqrtf(var + 1e-5f);
        float sh = bb[c] - mean * sc;
        scale[c] = sc;
        shift[c] = sh;
        shpb[c] = f2bf(sh / sc);
    }
}

// ---------------- FUSED GEMM12 (double-buffered z1t, 1 barrier/tile) ----------------
// z2 = bf16( relu(z1 + sh/sc) @ (diag(sc)*W2) + b2 ), z1 = A@W1 + b1 recomputed per tile
__global__ __launch_bounds__(256) void gemm12_kernel(const unsigned short* __restrict__ A,
        const unsigned short* __restrict__ w1t, const float* __restrict__ b1,
        const unsigned short* __restrict__ shpb, const float* __restrict__ scale1,
        const unsigned short* __restrict__ w2t, const float* __restrict__ b2,
        unsigned short* __restrict__ z2, float* __restrict__ part2) {
    __shared__ unsigned short z1t[2][16][264];  // double buffer: 1 barrier per tile
    __shared__ unsigned short sm2[4][16][44];
    int wave = threadIdx.x >> 6;
    int lane = threadIdx.x & 63;
    int l15 = lane & 15;
    int kg = lane >> 4;
    int rrow = lane >> 2;          // 0..15
    int rcol = (lane & 3) * 8;     // 0..31 step 8

    // gemm1 part: wave owns z1 cols [wave*64, wave*64+64)
    bf16x8 B1[4][4];
    float bs1[4];                  // b1 + sh/sc  (combined pre-relu shift)
#pragma unroll
    for (int t = 0; t < 4; ++t) {
        int col = (wave * 4 + t) * 16 + l15;
        bs1[t] = b1[col] + bf2f(shpb[col]);
#pragma unroll
        for (int kk = 0; kk < 4; ++kk)
            B1[t][kk] = *(const bf16x8*)(w1t + (size_t)col * D + kk * 32 + kg * 8);
    }
    // gemm2 part: wave owns z2 cols [wave*32, wave*32+32); B2 scaled by scale1 (per-k)
    bf16x8 B2[2][8];
    float bias2[2];
#pragma unroll
    for (int t = 0; t < 2; ++t) {
        int col = (wave * 2 + t) * 16 + l15;
        bias2[t] = b2[col];
#pragma unroll
        for (int kk = 0; kk < 8; ++kk) {
            bf16x8 raw = *(const bf16x8*)(w2t + (size_t)col * D2 + kk * 32 + kg * 8);
            int k0 = kk * 32 + kg * 8;
            const f32x4* sp = (const f32x4*)(scale1 + k0);
            f32x4 s0 = sp[0], s1 = sp[1];
            ushort8v bw;
#pragma unroll
            for (int j = 0; j < 4; ++j) {
                bw[j]     = f2bf_hw(bf2f((unsigned short)raw[j]) * s0[j]);
                bw[j + 4] = f2bf_hw(bf2f((unsigned short)raw[j + 4]) * s1[j]);
            }
            B2[t][kk] = __builtin_bit_cast(bf16x8, bw);
        }
    }

    float s[2] = {0.f, 0.f}, q[2] = {0.f, 0.f};

    int rt = blockIdx.x;
    int p = 0;
    bf16x8 afn[4];
    {
        int row = rt * 16 + l15;
#pragma unroll
        for (int kk = 0; kk < 4; ++kk)
            afn[kk] = *(const bf16x8*)(A + (size_t)row * D + kk * 32 + kg * 8);
    }
    while (rt < NROWT) {
        int rtn = rt + NBLK2;
        bf16x8 af[4];
#pragma unroll
        for (int kk = 0; kk < 4; ++kk) af[kk] = afn[kk];
        if (rtn < NROWT) {
            int row = rtn * 16 + l15;
#pragma unroll
            for (int kk = 0; kk < 4; ++kk)
                afn[kk] = *(const bf16x8*)(A + (size_t)row * D + kk * 32 + kg * 8);
        }
        // z1 tile (16 rows x 64 cols per wave)
        f32x4 acc1[4];
#pragma unroll
        for (int t = 0; t < 4; ++t) acc1[t] = (f32x4){0.f, 0.f, 0.f, 0.f};
#pragma unroll
        for (int kk = 0; kk < 4; ++kk)
#pragma unroll
            for (int t = 0; t < 4; ++t)
                acc1[t] = __builtin_amdgcn_mfma_f32_16x16x32_bf16(af[kk], B1[t][kk], acc1[t], 0, 0, 0);
        // write to buffer p (other buffer may still be being read — safe)
#pragma unroll
        for (int t = 0; t < 4; ++t) {
            int col = (wave * 4 + t) * 16 + l15;
#pragma unroll
            for (int r = 0; r < 4; ++r)
                z1t[p][kg * 4 + r][col] = f2bf_hw(fmaxf(acc1[t][r] + bs1[t], 0.f));
        }
        __syncthreads();   // buffer p complete for all waves
        // gemm2: read K=256 fragments from LDS buffer p
        f32x4 acc2[2];
        acc2[0] = (f32x4){0.f, 0.f, 0.f, 0.f};
        acc2[1] = (f32x4){0.f, 0.f, 0.f, 0.f};
#pragma unroll
        for (int kk = 0; kk < 8; ++kk) {
            bf16x8 a2 = __builtin_bit_cast(bf16x8, *(const ushort8v*)&z1t[p][l15][kk * 32 + kg * 8]);
            acc2[0] = __builtin_amdgcn_mfma_f32_16x16x32_bf16(a2, B2[0][kk], acc2[0], 0, 0, 0);
            acc2[1] = __builtin_amdgcn_mfma_f32_16x16x32_bf16(a2, B2[1][kk], acc2[1], 0, 0, 0);
        }
#pragma unroll
        for (int t = 0; t < 2; ++t) {
#pragma unroll
            for (int r = 0; r < 4; ++r) {
                float va = acc2[t][r] + bias2[t];
                s[t] += va;
                q[t] = fmaf(va, va, q[t]);
                sm2[wave][kg * 4 + r][t * 16 + l15] = f2bf_hw(va);
            }
        }
        ushort8v v0 = *(const ushort8v*)&sm2[wave][rrow][rcol];
        *(ushort8v*)(z2 + (size_t)(rt * 16 + rrow) * D + wave * 32 + rcol) = v0;
        p ^= 1;
        rt = rtn;
    }
#pragma unroll
    for (int t = 0; t < 2; ++t) {
        s[t] += __shfl_xor(s[t], 16); s[t] += __shfl_xor(s[t], 32);
        q[t] += __shfl_xor(q[t], 16); q[t] += __shfl_xor(q[t], 32);
        if (kg == 0) {
            int col = (wave * 2 + t) * 16 + l15;
            part2[(size_t)blockIdx.x * 256 + col] = s[t];
            part2[(size_t)blockIdx.x * 256 + 128 + col] = q[t];
        }
    }
}

// ---------------- final: hbf = bf16(relu(bn2(z2)) + hbf)  [last: h_f32 = bn2(z2)+hbf] ----------------
__global__ __launch_bounds__(256) void final_kernel(const unsigned short* __restrict__ z2,
        const float* __restrict__ scale, const float* __restrict__ shift,
        unsigned short* __restrict__ hbf, float* __restrict__ hout, int last) {
    int i = blockIdx.x * 256 + threadIdx.x;
    int base = i * 8;
    int c = base & (D - 1);
    f32x4 sc0 = *(const f32x4*)(scale + c);
    f32x4 sc1 = *(const f32x4*)(scale + c + 4);
    f32x4 sh0 = *(const f32x4*)(shift + c);
    f32x4 sh1 = *(const f32x4*)(shift + c + 4);
    ushort8v zv = *(const ushort8v*)(z2 + base);
    ushort8v hv = *(const ushort8v*)(hbf + base);
    if (last) {
        f32x4 o0, o1;
#pragma unroll
        for (int j = 0; j < 4; ++j) {
            o0[j] = fmaf(bf2f(zv[j]), sc0[j], sh0[j]) + bf2f(hv[j]);
            o1[j] = fmaf(bf2f(zv[j + 4]), sc1[j], sh1[j]) + bf2f(hv[j + 4]);
        }
        *(f32x4*)(hout + base) = o0;
        *(f32x4*)(hout + base + 4) = o1;
    } else {
        ushort8v ob;
#pragma unroll
        for (int j = 0; j < 4; ++j) {
            float v0 = fmaxf(fmaf(bf2f(zv[j]), sc0[j], sh0[j]), 0.f) + bf2f(hv[j]);
            float v1 = fmaxf(fmaf(bf2f(zv[j + 4]), sc1[j], sh1[j]), 0.f) + bf2f(hv[j + 4]);
            ob[j] = f2bf_hw(v0);
            ob[j + 4] = f2bf_hw(v1);
        }
        *(ushort8v*)(hbf + base) = ob;
    }
}

extern "C" void kernel_launch(void* const* d_in, const int* in_sizes, int n_in,
                              void* d_out, int out_size, void* d_ws, size_t ws_size,
                              hipStream_t stream) {
    const int* x = (const int*)d_in[0];
    const int* ei = (const int*)d_in[1];
    const int* ea = (const int*)d_in[2];
    const float* aemb = (const float*)d_in[4];
    const float* bemb = (const float*)d_in[5];
    const float* eps = (const float*)d_in[6];
    const float* W1 = (const float*)d_in[7];
    const float* b1 = (const float*)d_in[8];
    const float* bn1g = (const float*)d_in[9];
    const float* bn1b = (const float*)d_in[10];
    const float* W2 = (const float*)d_in[11];
    const float* b2 = (const float*)d_in[12];
    const float* bng = (const float*)d_in[13];
    const float* bnb = (const float*)d_in[14];
    float* h = (float*)d_out;

    char* ws = (char*)d_ws;
    size_t off = 0;
    auto alloc = [&](size_t bytes) {
        void* p = ws + off;
        off += (bytes + 255) & ~(size_t)255;
        return p;
    };
    unsigned short* Az2 = (unsigned short*)alloc((size_t)N_NODES * D * 2);   // 38.4MB (A aliases z2)
    unsigned short* hbf = (unsigned short*)alloc((size_t)N_NODES * D * 2);   // 38.4MB bf16 h
    unsigned short* w1t = (unsigned short*)alloc((size_t)NLAYER * D2 * D * 2);
    unsigned short* w2t = (unsigned short*)alloc((size_t)NLAYER * D * D2 * 2);
    float* combo        = (float*)alloc((size_t)NLAYER * 216 * D * 4);
    int* bins           = (int*)alloc((size_t)N_EDGES * 4);
    int* row_start      = (int*)alloc((size_t)(NB1 * 256) * 4);
    int* deg            = (int*)alloc((size_t)(NB1 * 256) * 4);
    int* cursor         = (int*)alloc((size_t)(NB1 * 256) * 4);
    int* part           = (int*)alloc((size_t)(NB1 * 256) * 4);
    int* bsum           = (int*)alloc(1024 * 4);
    int* boff           = (int*)alloc(1024 * 4);
    int* perm           = (int*)alloc((size_t)(NB1 * 256) * 4);
    int* bcnt           = (int*)alloc(256 * 4);
    int* bstart         = (int*)alloc(256 * 4);
    int* gcur           = (int*)alloc(256 * 4);
    float* part1        = (float*)alloc((size_t)NBLK1 * 512 * 4);   // 1.0MB
    float* part2        = (float*)alloc((size_t)NBLK2 * 256 * 4);   // 0.5MB
    float* scale1 = (float*)alloc(256 * 4);
    float* shift1 = (float*)alloc(256 * 4);
    float* scale2 = (float*)alloc(128 * 4);
    float* shift2 = (float*)alloc(128 * 4);
    unsigned short* shp1 = (unsigned short*)alloc(256 * 2);
    unsigned short* shp2 = (unsigned short*)alloc(128 * 2);

    // one-time prep
    prepw_kernel<<<(NLAYER * D2 * D + 255) / 256, 256, 0, stream>>>(W1, W2, w1t, w2t);
    combo_kernel<<<NLAYER * 216, 128, 0, stream>>>(bemb, combo);
    atom_enc_kernel<<<N_NODES / 8, 256, 0, stream>>>(x, aemb, hbf);

    // CSR build (by dst) + degree-bucketed perm
    hipMemsetAsync(deg, 0, (size_t)(NB1 * 256) * 4, stream);
    hipMemsetAsync(cursor, 0, (size_t)(NB1 * 256) * 4, stream);
    hipMemsetAsync(bcnt, 0, 256 * 4, stream);
    hipMemsetAsync(gcur, 0, 256 * 4, stream);
    hist_kernel<<<(N_EDGES + 255) / 256, 256, 0, stream>>>(ei, deg);
    scan1_kernel<<<NB1, 256, 0, stream>>>(deg, part, bsum);
    scan2_kernel<<<1, 1024, 0, stream>>>(bsum, boff);
    scan3_kernel<<<NB1, 256, 0, stream>>>(part, boff, row_start);
    bin_kernel<<<(N_EDGES + 255) / 256, 256, 0, stream>>>(ei, ea, row_start, cursor, bins);
    bucket_hist_kernel<<<NB1, 256, 0, stream>>>(deg, bcnt);
    bucket_scan_kernel<<<1, 64, 0, stream>>>(bcnt, bstart);
    bucket_scatter_kernel<<<NB1, 256, 0, stream>>>(deg, bstart, gcur, perm);

    for (int l = 0; l < NLAYER; ++l) {
        aggr_kernel<<<N_NODES / 16, 256, 0, stream>>>(perm, row_start, deg, bins,
                combo + l * 216 * D, hbf, eps + l, Az2);
        gemm1s_kernel<<<NBLK1, 256, 0, stream>>>(Az2, w1t + l * D2 * D,
                b1 + l * D2, part1);
        reduce_finalize_kernel<<<256, 256, 0, stream>>>(part1, NBLK1, D2,
                bn1g + l * D2, bn1b + l * D2, scale1, shift1, shp1);
        gemm12_kernel<<<NBLK2, 256, 0, stream>>>(Az2, w1t + l * D2 * D,
                b1 + l * D2, shp1, scale1, w2t + l * D * D2, b2 + l * D, Az2, part2);
        reduce_finalize_kernel<<<128, 256, 0, stream>>>(part2, NBLK2, D,
                bng + l * D, bnb + l * D, scale2, shift2, shp2);
        final_kernel<<<(N_NODES * D / 8) / 256, 256, 0, stream>>>(Az2, scale2, shift2,
                hbf, h, (l == NLAYER - 1) ? 1 : 0);
    }
}

// Round 24
// 695.420 us; speedup vs baseline: 1.9664x; 1.0522x over previous
//
#include <hip/hip_runtime.h>

#define N_NODES 150000
#define N_EDGES 500000
#define D 128
#define D2 256
#define NLAYER 5
#define NB1 586    // ceil(N_NODES/256)
#define NROWT 9375 // N_NODES/16 (exact)
#define NBLK1 512  // gemm1s persistent blocks
#define NBLK2 512  // gemm12 persistent blocks

typedef __attribute__((ext_vector_type(8))) short bf16x8;
typedef __attribute__((ext_vector_type(4))) float f32x4;
typedef __attribute__((ext_vector_type(4))) unsigned short ushort4v;
typedef __attribute__((ext_vector_type(8))) unsigned short ushort8v;
typedef __attribute__((ext_vector_type(4))) unsigned int u32x4;

__device__ __forceinline__ unsigned short f2bf(float f) {
    unsigned int u = __builtin_bit_cast(unsigned int, f);
    u += 0x7fffu + ((u >> 16) & 1u);
    return (unsigned short)(u >> 16);
}
// HW path: compiler lowers to v_cvt_pk_bf16_f32 and fuses pairs (m240)
__device__ __forceinline__ unsigned short f2bf_hw(float f) {
    return __builtin_bit_cast(unsigned short, (__bf16)f);
}
__device__ __forceinline__ float bf2f(unsigned short s) {
    unsigned int u = ((unsigned int)s) << 16;
    return __builtin_bit_cast(float, u);
}

// ---------------- weight transpose + bf16 convert ----------------
__global__ __launch_bounds__(256) void prepw_kernel(const float* __restrict__ W1,
        const float* __restrict__ W2, unsigned short* __restrict__ w1t,
        unsigned short* __restrict__ w2t) {
    int i = blockIdx.x * 256 + threadIdx.x;
    if (i < NLAYER * D2 * D) {
        int l = i / (D2 * D);
        int rem = i % (D2 * D);
        int n = rem / D;
        int k = rem % D;
        w1t[i] = f2bf(W1[(l * D + k) * D2 + n]);
    }
    if (i < NLAYER * D * D2) {
        int l = i / (D * D2);
        int rem = i % (D * D2);
        int n = rem / D2;
        int k = rem % D2;
        w2t[i] = f2bf(W2[(l * D2 + k) * D + n]);
    }
}

// ---------------- bond combo table ----------------
__global__ __launch_bounds__(128) void combo_kernel(const float* __restrict__ bemb,
        float* __restrict__ combo) {
    int b = blockIdx.x;            // l*216 + p
    int l = b / 216, p = b % 216;
    int a0 = p % 6, a1 = (p / 6) % 6, a2 = p / 36;
    int d = threadIdx.x;
    combo[b * D + d] = bemb[((l * 3 + 0) * 6 + a0) * D + d]
                     + bemb[((l * 3 + 1) * 6 + a1) * D + d]
                     + bemb[((l * 3 + 2) * 6 + a2) * D + d];
}

// ---------------- atom encoder (bf16 h only) ----------------
__global__ __launch_bounds__(256) void atom_enc_kernel(const int* __restrict__ x,
        const float* __restrict__ aemb, unsigned short* __restrict__ hbf) {
    int node = blockIdx.x * 8 + (threadIdx.x >> 5);
    int t = threadIdx.x & 31;
    int d0 = t * 4;
    f32x4 s = {0, 0, 0, 0};
#pragma unroll
    for (int f = 0; f < 9; ++f) {
        int xi = x[node * 9 + f];
        f32x4 v = *(const f32x4*)(aemb + (size_t)(f * 119 + xi) * D + d0);
        s[0] += v[0]; s[1] += v[1]; s[2] += v[2]; s[3] += v[3];
    }
    ushort4v o;
#pragma unroll
    for (int j = 0; j < 4; ++j) o[j] = f2bf_hw(s[j]);
    *(ushort4v*)(hbf + (size_t)node * D + d0) = o;
}

// ---------------- CSR build ----------------
__global__ __launch_bounds__(256) void hist_kernel(const int* __restrict__ ei,
        int* __restrict__ deg) {
    int e = blockIdx.x * 256 + threadIdx.x;
    if (e < N_EDGES) atomicAdd(&deg[ei[N_EDGES + e]], 1);
}

__global__ __launch_bounds__(256) void scan1_kernel(const int* __restrict__ deg,
        int* __restrict__ part, int* __restrict__ bsum) {
    __shared__ int sd[256];
    int tid = threadIdx.x;
    int i = blockIdx.x * 256 + tid;
    int v = (i < N_NODES) ? deg[i] : 0;
    sd[tid] = v;
    __syncthreads();
    for (int off = 1; off < 256; off <<= 1) {
        int t = (tid >= off) ? sd[tid - off] : 0;
        __syncthreads();
        sd[tid] += t;
        __syncthreads();
    }
    if (i < N_NODES) part[i] = sd[tid] - v;
    if (tid == 255) bsum[blockIdx.x] = sd[255];
}

__global__ __launch_bounds__(1024) void scan2_kernel(const int* __restrict__ bsum,
        int* __restrict__ boff) {
    __shared__ int sd[1024];
    int tid = threadIdx.x;
    int v = (tid < NB1) ? bsum[tid] : 0;
    sd[tid] = v;
    __syncthreads();
    for (int off = 1; off < 1024; off <<= 1) {
        int t = (tid >= off) ? sd[tid - off] : 0;
        __syncthreads();
        sd[tid] += t;
        __syncthreads();
    }
    if (tid < NB1) boff[tid] = sd[tid] - v;
}

__global__ __launch_bounds__(256) void scan3_kernel(const int* __restrict__ part,
        const int* __restrict__ boff, int* __restrict__ row_start) {
    int i = blockIdx.x * 256 + threadIdx.x;
    if (i < N_NODES) row_start[i] = part[i] + boff[i >> 8];
}

__global__ __launch_bounds__(256) void bin_kernel(const int* __restrict__ ei,
        const int* __restrict__ ea, const int* __restrict__ row_start,
        int* __restrict__ cursor, int* __restrict__ bins) {
    int e = blockIdx.x * 256 + threadIdx.x;
    if (e >= N_EDGES) return;
    int dst = ei[N_EDGES + e];
    int pos = row_start[dst] + atomicAdd(&cursor[dst], 1);
    int pack = ea[e * 3 + 0] + ea[e * 3 + 1] * 6 + ea[e * 3 + 2] * 36;
    bins[pos] = ei[e] | (pack << 18);
}

// ---------------- aggregation + A-build (4 nodes/wave, 2-deep pipelined gather) ----------------
__global__ __launch_bounds__(256) void aggr_kernel(const int* __restrict__ row_start,
        const int* __restrict__ deg, const int* __restrict__ bins,
        const float* __restrict__ combo, const unsigned short* __restrict__ hbf,
        const float* __restrict__ epsp, unsigned short* __restrict__ A) {
    int wid = threadIdx.x >> 6;
    int lane = threadIdx.x & 63;
    int sub = lane >> 4;               // node slot 0..3 within wave
    int t = lane & 15;
    int d0 = t * 8;
    int node = blockIdx.x * 16 + wid * 4 + sub;
    float ke = 1.0f + epsp[0];
    int start = row_start[node];
    int dg = deg[node];
    f32x4 s0 = {0, 0, 0, 0}, s1 = {0, 0, 0, 0};

    // pipeline state: e_nxt = bins entry for i+1; cur data for i
    int e_cur = (dg > 0) ? bins[start] : 0;
    int e_nxt = (dg > 1) ? bins[start + 1] : 0;
    ushort8v hv = {0,0,0,0,0,0,0,0};
    f32x4 c0 = {0,0,0,0}, c1 = {0,0,0,0};
    if (dg > 0) {
        int src = e_cur & 0x3FFFF;
        int pack = e_cur >> 18;
        hv = *(const ushort8v*)(hbf + (size_t)src * D + d0);
        c0 = *(const f32x4*)(combo + pack * D + d0);
        c1 = *(const f32x4*)(combo + pack * D + d0 + 4);
    }
    for (int i = 0; i < dg; ++i) {
        int e2 = (i + 2 < dg) ? bins[start + i + 2] : 0;
        ushort8v hvn = {0,0,0,0,0,0,0,0};
        f32x4 c0n = {0,0,0,0}, c1n = {0,0,0,0};
        if (i + 1 < dg) {
            int src = e_nxt & 0x3FFFF;
            int pack = e_nxt >> 18;
            hvn = *(const ushort8v*)(hbf + (size_t)src * D + d0);
            c0n = *(const f32x4*)(combo + pack * D + d0);
            c1n = *(const f32x4*)(combo + pack * D + d0 + 4);
        }
#pragma unroll
        for (int j = 0; j < 4; ++j) {
            s0[j] += fmaxf(bf2f(hv[j]) + c0[j], 0.f);
            s1[j] += fmaxf(bf2f(hv[j + 4]) + c1[j], 0.f);
        }
        hv = hvn; c0 = c0n; c1 = c1n;
        e_nxt = e2;
    }
    ushort8v hs = *(const ushort8v*)(hbf + (size_t)node * D + d0);
    ushort8v o;
#pragma unroll
    for (int j = 0; j < 4; ++j) {
        o[j]     = f2bf_hw(ke * bf2f(hs[j]) + s0[j]);
        o[j + 4] = f2bf_hw(ke * bf2f(hs[j + 4]) + s1[j]);
    }
    *(ushort8v*)(A + (size_t)node * D + d0) = o;
}

// ---------------- GEMM1-STATS (persistent, B-resident, NO z1 store) ----------------
__global__ __launch_bounds__(256) void gemm1s_kernel(const unsigned short* __restrict__ A,
        const unsigned short* __restrict__ w1t, const float* __restrict__ b1,
        float* __restrict__ part1) {
    int wave = threadIdx.x >> 6;
    int lane = threadIdx.x & 63;
    int l15 = lane & 15;
    int kg = lane >> 4;

    bf16x8 B[4][4];
    float bias[4];
#pragma unroll
    for (int t = 0; t < 4; ++t) {
        int col = (wave * 4 + t) * 16 + l15;
        bias[t] = b1[col];
#pragma unroll
        for (int kk = 0; kk < 4; ++kk)
            B[t][kk] = *(const bf16x8*)(w1t + (size_t)col * D + kk * 32 + kg * 8);
    }
    float s[4] = {0.f, 0.f, 0.f, 0.f}, q[4] = {0.f, 0.f, 0.f, 0.f};

    int rt = blockIdx.x;
    bf16x8 afn[4];
    {
        int row = rt * 16 + l15;
#pragma unroll
        for (int kk = 0; kk < 4; ++kk)
            afn[kk] = *(const bf16x8*)(A + (size_t)row * D + kk * 32 + kg * 8);
    }
    while (rt < NROWT) {
        int rtn = rt + NBLK1;
        bf16x8 af[4];
#pragma unroll
        for (int kk = 0; kk < 4; ++kk) af[kk] = afn[kk];
        if (rtn < NROWT) {
            int row = rtn * 16 + l15;
#pragma unroll
            for (int kk = 0; kk < 4; ++kk)
                afn[kk] = *(const bf16x8*)(A + (size_t)row * D + kk * 32 + kg * 8);
        }
        f32x4 acc[4];
#pragma unroll
        for (int t = 0; t < 4; ++t) acc[t] = (f32x4){0.f, 0.f, 0.f, 0.f};
#pragma unroll
        for (int kk = 0; kk < 4; ++kk)
#pragma unroll
            for (int t = 0; t < 4; ++t)
                acc[t] = __builtin_amdgcn_mfma_f32_16x16x32_bf16(af[kk], B[t][kk], acc[t], 0, 0, 0);
#pragma unroll
        for (int t = 0; t < 4; ++t) {
#pragma unroll
            for (int r = 0; r < 4; ++r) {
                float va = acc[t][r] + bias[t];
                s[t] += va;
                q[t] = fmaf(va, va, q[t]);
            }
        }
        rt = rtn;
    }
#pragma unroll
    for (int t = 0; t < 4; ++t) {
        s[t] += __shfl_xor(s[t], 16); s[t] += __shfl_xor(s[t], 32);
        q[t] += __shfl_xor(q[t], 16); q[t] += __shfl_xor(q[t], 32);
        if (kg == 0) {
            int col = (wave * 4 + t) * 16 + l15;
            part1[(size_t)blockIdx.x * 512 + col] = s[t];
            part1[(size_t)blockIdx.x * 512 + 256 + col] = q[t];
        }
    }
}

// ---------------- reduce partials + finalize BN ----------------
// outputs: scale(f32), shift(f32), shpb(bf16 of shift/scale, for BN1-fold)
__global__ __launch_bounds__(256) void reduce_finalize_kernel(const float* __restrict__ part,
        int nblk, int C, const float* __restrict__ g, const float* __restrict__ bb,
        float* __restrict__ scale, float* __restrict__ shift,
        unsigned short* __restrict__ shpb) {
    int c = blockIdx.x;
    int tid = threadIdx.x;
    float s = 0.f, q = 0.f;
    for (int i = tid; i < nblk; i += 256) {
        s += part[(size_t)i * 2 * C + c];
        q += part[(size_t)i * 2 * C + C + c];
    }
#pragma unroll
    for (int off = 1; off < 64; off <<= 1) {
        s += __shfl_xor(s, off);
        q += __shfl_xor(q, off);
    }
    __shared__ float rs[4], rq[4];
    int w = tid >> 6;
    if ((tid & 63) == 0) { rs[w] = s; rq[w] = q; }
    __syncthreads();
    if (tid == 0) {
        s = rs[0] + rs[1] + rs[2] + rs[3];
        q = rq[0] + rq[1] + rq[2] + rq[3];
        float inv_n = 1.0f / (float)N_NODES;
        float mean = s * inv_n;
        float var = q * inv_n - mean * mean;
        float sc = g[c] * rsqrtf(var + 1e-5f);
        float sh = bb[c] - mean * sc;
        scale[c] = sc;
        shift[c] = sh;
        shpb[c] = f2bf(sh / sc);
    }
}

// ---------------- FUSED GEMM12: recompute z1 tile in regs, bn1+relu -> LDS, gemm2 ----------------
// z2 = bf16( relu(z1 + sh/sc) @ (diag(sc)*W2) + b2 ), z1 = A@W1 + b1 recomputed per tile
__global__ __launch_bounds__(256) void gemm12_kernel(const unsigned short* __restrict__ A,
        const unsigned short* __restrict__ w1t, const float* __restrict__ b1,
        const unsigned short* __restrict__ shpb, const float* __restrict__ scale1,
        const unsigned short* __restrict__ w2t, const float* __restrict__ b2,
        unsigned short* __restrict__ z2, float* __restrict__ part2) {
    __shared__ unsigned short z1t[16][264];   // 16 rows x 256 cols, pad 8 (stride 528B: 2-way = free)
    __shared__ unsigned short sm2[4][16][44];
    int wave = threadIdx.x >> 6;
    int lane = threadIdx.x & 63;
    int l15 = lane & 15;
    int kg = lane >> 4;
    int rrow = lane >> 2;          // 0..15
    int rcol = (lane & 3) * 8;     // 0..31 step 8

    // gemm1 part: wave owns z1 cols [wave*64, wave*64+64)
    bf16x8 B1[4][4];
    float bs1[4];                  // b1 + sh/sc  (combined pre-relu shift)
#pragma unroll
    for (int t = 0; t < 4; ++t) {
        int col = (wave * 4 + t) * 16 + l15;
        bs1[t] = b1[col] + bf2f(shpb[col]);
#pragma unroll
        for (int kk = 0; kk < 4; ++kk)
            B1[t][kk] = *(const bf16x8*)(w1t + (size_t)col * D + kk * 32 + kg * 8);
    }
    // gemm2 part: wave owns z2 cols [wave*32, wave*32+32); B2 scaled by scale1 (per-k)
    bf16x8 B2[2][8];
    float bias2[2];
#pragma unroll
    for (int t = 0; t < 2; ++t) {
        int col = (wave * 2 + t) * 16 + l15;
        bias2[t] = b2[col];
#pragma unroll
        for (int kk = 0; kk < 8; ++kk) {
            bf16x8 raw = *(const bf16x8*)(w2t + (size_t)col * D2 + kk * 32 + kg * 8);
            int k0 = kk * 32 + kg * 8;
            const f32x4* sp = (const f32x4*)(scale1 + k0);
            f32x4 s0 = sp[0], s1 = sp[1];
            ushort8v bw;
#pragma unroll
            for (int j = 0; j < 4; ++j) {
                bw[j]     = f2bf_hw(bf2f((unsigned short)raw[j]) * s0[j]);
                bw[j + 4] = f2bf_hw(bf2f((unsigned short)raw[j + 4]) * s1[j]);
            }
            B2[t][kk] = __builtin_bit_cast(bf16x8, bw);
        }
    }

    float s[2] = {0.f, 0.f}, q[2] = {0.f, 0.f};

    int rt = blockIdx.x;
    bf16x8 afn[4];
    {
        int row = rt * 16 + l15;
#pragma unroll
        for (int kk = 0; kk < 4; ++kk)
            afn[kk] = *(const bf16x8*)(A + (size_t)row * D + kk * 32 + kg * 8);
    }
    while (rt < NROWT) {
        int rtn = rt + NBLK2;
        bf16x8 af[4];
#pragma unroll
        for (int kk = 0; kk < 4; ++kk) af[kk] = afn[kk];
        if (rtn < NROWT) {
            int row = rtn * 16 + l15;
#pragma unroll
            for (int kk = 0; kk < 4; ++kk)
                afn[kk] = *(const bf16x8*)(A + (size_t)row * D + kk * 32 + kg * 8);
        }
        // z1 tile (16 rows x 64 cols per wave)
        f32x4 acc1[4];
#pragma unroll
        for (int t = 0; t < 4; ++t) acc1[t] = (f32x4){0.f, 0.f, 0.f, 0.f};
#pragma unroll
        for (int kk = 0; kk < 4; ++kk)
#pragma unroll
            for (int t = 0; t < 4; ++t)
                acc1[t] = __builtin_amdgcn_mfma_f32_16x16x32_bf16(af[kk], B1[t][kk], acc1[t], 0, 0, 0);
        __syncthreads();   // prior iteration's z1t reads complete
#pragma unroll
        for (int t = 0; t < 4; ++t) {
            int col = (wave * 4 + t) * 16 + l15;
#pragma unroll
            for (int r = 0; r < 4; ++r)
                z1t[kg * 4 + r][col] = f2bf_hw(fmaxf(acc1[t][r] + bs1[t], 0.f));
        }
        __syncthreads();   // z1t tile complete
        // gemm2: read K=256 fragments from LDS
        f32x4 acc2[2];
        acc2[0] = (f32x4){0.f, 0.f, 0.f, 0.f};
        acc2[1] = (f32x4){0.f, 0.f, 0.f, 0.f};
#pragma unroll
        for (int kk = 0; kk < 8; ++kk) {
            bf16x8 a2 = __builtin_bit_cast(bf16x8, *(const ushort8v*)&z1t[l15][kk * 32 + kg * 8]);
            acc2[0] = __builtin_amdgcn_mfma_f32_16x16x32_bf16(a2, B2[0][kk], acc2[0], 0, 0, 0);
            acc2[1] = __builtin_amdgcn_mfma_f32_16x16x32_bf16(a2, B2[1][kk], acc2[1], 0, 0, 0);
        }
#pragma unroll
        for (int t = 0; t < 2; ++t) {
#pragma unroll
            for (int r = 0; r < 4; ++r) {
                float va = acc2[t][r] + bias2[t];
                s[t] += va;
                q[t] = fmaf(va, va, q[t]);
                sm2[wave][kg * 4 + r][t * 16 + l15] = f2bf_hw(va);
            }
        }
        ushort8v v0 = *(const ushort8v*)&sm2[wave][rrow][rcol];
        *(ushort8v*)(z2 + (size_t)(rt * 16 + rrow) * D + wave * 32 + rcol) = v0;
        rt = rtn;
    }
#pragma unroll
    for (int t = 0; t < 2; ++t) {
        s[t] += __shfl_xor(s[t], 16); s[t] += __shfl_xor(s[t], 32);
        q[t] += __shfl_xor(q[t], 16); q[t] += __shfl_xor(q[t], 32);
        if (kg == 0) {
            int col = (wave * 2 + t) * 16 + l15;
            part2[(size_t)blockIdx.x * 256 + col] = s[t];
            part2[(size_t)blockIdx.x * 256 + 128 + col] = q[t];
        }
    }
}

// ---------------- final: hbf = bf16(relu(bn2(z2)) + hbf)  [last: h_f32 = bn2(z2)+hbf] ----------------
__global__ __launch_bounds__(256) void final_kernel(const unsigned short* __restrict__ z2,
        const float* __restrict__ scale, const float* __restrict__ shift,
        unsigned short* __restrict__ hbf, float* __restrict__ hout, int last) {
    int i = blockIdx.x * 256 + threadIdx.x;
    int base = i * 8;
    int c = base & (D - 1);
    f32x4 sc0 = *(const f32x4*)(scale + c);
    f32x4 sc1 = *(const f32x4*)(scale + c + 4);
    f32x4 sh0 = *(const f32x4*)(shift + c);
    f32x4 sh1 = *(const f32x4*)(shift + c + 4);
    ushort8v zv = *(const ushort8v*)(z2 + base);
    ushort8v hv = *(const ushort8v*)(hbf + base);
    if (last) {
        f32x4 o0, o1;
#pragma unroll
        for (int j = 0; j < 4; ++j) {
            o0[j] = fmaf(bf2f(zv[j]), sc0[j], sh0[j]) + bf2f(hv[j]);
            o1[j] = fmaf(bf2f(zv[j + 4]), sc1[j], sh1[j]) + bf2f(hv[j + 4]);
        }
        *(f32x4*)(hout + base) = o0;
        *(f32x4*)(hout + base + 4) = o1;
    } else {
        ushort8v ob;
#pragma unroll
        for (int j = 0; j < 4; ++j) {
            float v0 = fmaxf(fmaf(bf2f(zv[j]), sc0[j], sh0[j]), 0.f) + bf2f(hv[j]);
            float v1 = fmaxf(fmaf(bf2f(zv[j + 4]), sc1[j], sh1[j]), 0.f) + bf2f(hv[j + 4]);
            ob[j] = f2bf_hw(v0);
            ob[j + 4] = f2bf_hw(v1);
        }
        *(ushort8v*)(hbf + base) = ob;
    }
}

extern "C" void kernel_launch(void* const* d_in, const int* in_sizes, int n_in,
                              void* d_out, int out_size, void* d_ws, size_t ws_size,
                              hipStream_t stream) {
    const int* x = (const int*)d_in[0];
    const int* ei = (const int*)d_in[1];
    const int* ea = (const int*)d_in[2];
    const float* aemb = (const float*)d_in[4];
    const float* bemb = (const float*)d_in[5];
    const float* eps = (const float*)d_in[6];
    const float* W1 = (const float*)d_in[7];
    const float* b1 = (const float*)d_in[8];
    const float* bn1g = (const float*)d_in[9];
    const float* bn1b = (const float*)d_in[10];
    const float* W2 = (const float*)d_in[11];
    const float* b2 = (const float*)d_in[12];
    const float* bng = (const float*)d_in[13];
    const float* bnb = (const float*)d_in[14];
    float* h = (float*)d_out;

    char* ws = (char*)d_ws;
    size_t off = 0;
    auto alloc = [&](size_t bytes) {
        void* p = ws + off;
        off += (bytes + 255) & ~(size_t)255;
        return p;
    };
    unsigned short* Az2 = (unsigned short*)alloc((size_t)N_NODES * D * 2);   // 38.4MB (A aliases z2)
    unsigned short* hbf = (unsigned short*)alloc((size_t)N_NODES * D * 2);   // 38.4MB bf16 h
    unsigned short* w1t = (unsigned short*)alloc((size_t)NLAYER * D2 * D * 2);
    unsigned short* w2t = (unsigned short*)alloc((size_t)NLAYER * D * D2 * 2);
    float* combo        = (float*)alloc((size_t)NLAYER * 216 * D * 4);
    int* bins           = (int*)alloc((size_t)N_EDGES * 4);
    int* row_start      = (int*)alloc((size_t)(NB1 * 256) * 4);
    int* deg            = (int*)alloc((size_t)(NB1 * 256) * 4);
    int* cursor         = (int*)alloc((size_t)(NB1 * 256) * 4);
    int* part           = (int*)alloc((size_t)(NB1 * 256) * 4);
    int* bsum           = (int*)alloc(1024 * 4);
    int* boff           = (int*)alloc(1024 * 4);
    float* part1        = (float*)alloc((size_t)NBLK1 * 512 * 4);   // 1.0MB
    float* part2        = (float*)alloc((size_t)NBLK2 * 256 * 4);   // 0.5MB
    float* scale1 = (float*)alloc(256 * 4);
    float* shift1 = (float*)alloc(256 * 4);
    float* scale2 = (float*)alloc(128 * 4);
    float* shift2 = (float*)alloc(128 * 4);
    unsigned short* shp1 = (unsigned short*)alloc(256 * 2);
    unsigned short* shp2 = (unsigned short*)alloc(128 * 2);

    // one-time prep
    prepw_kernel<<<(NLAYER * D2 * D + 255) / 256, 256, 0, stream>>>(W1, W2, w1t, w2t);
    combo_kernel<<<NLAYER * 216, 128, 0, stream>>>(bemb, combo);
    atom_enc_kernel<<<N_NODES / 8, 256, 0, stream>>>(x, aemb, hbf);

    // CSR build (by dst)
    hipMemsetAsync(deg, 0, (size_t)(NB1 * 256) * 4, stream);
    hipMemsetAsync(cursor, 0, (size_t)(NB1 * 256) * 4, stream);
    hist_kernel<<<(N_EDGES + 255) / 256, 256, 0, stream>>>(ei, deg);
    scan1_kernel<<<NB1, 256, 0, stream>>>(deg, part, bsum);
    scan2_kernel<<<1, 1024, 0, stream>>>(bsum, boff);
    scan3_kernel<<<NB1, 256, 0, stream>>>(part, boff, row_start);
    bin_kernel<<<(N_EDGES + 255) / 256, 256, 0, stream>>>(ei, ea, row_start, cursor, bins);

    for (int l = 0; l < NLAYER; ++l) {
        aggr_kernel<<<N_NODES / 16, 256, 0, stream>>>(row_start, deg, bins,
                combo + l * 216 * D, hbf, eps + l, Az2);
        gemm1s_kernel<<<NBLK1, 256, 0, stream>>>(Az2, w1t + l * D2 * D,
                b1 + l * D2, part1);
        reduce_finalize_kernel<<<256, 256, 0, stream>>>(part1, NBLK1, D2,
                bn1g + l * D2, bn1b + l * D2, scale1, shift1, shp1);
        gemm12_kernel<<<NBLK2, 256, 0, stream>>>(Az2, w1t + l * D2 * D,
                b1 + l * D2, shp1, scale1, w2t + l * D * D2, b2 + l * D, Az2, part2);
        reduce_finalize_kernel<<<128, 256, 0, stream>>>(part2, NBLK2, D,
                bng + l * D, bnb + l * D, scale2, shift2, shp2);
        final_kernel<<<(N_NODES * D / 8) / 256, 256, 0, stream>>>(Az2, scale2, shift2,
                hbf, h, (l == NLAYER - 1) ? 1 : 0);
    }
}